// Round 7
// baseline (33.767 us; speedup 1.0000x reference)
//
#include <hip/hip_runtime.h>

#define DIM_HID 65536
#define NKERS   500
#define NQ      4                    // quarters per row
#define QCHUNK  (DIM_HID / NQ)       // 16384 floats per quarter

#define ITILE   16                   // i's per expand_part block
#define NIB     32                   // 32 * 16 = 512 >= 500
#define JPAD    512                  // padded j extent for partials

typedef float f4 __attribute__((ext_vector_type(4)));

// Kernel 1: partial GEMV. Block (row, q) computes
//   ws[row*4+q] = dot(W[row, q*QCHUNK:(q+1)*QCHUNK], x[q*QCHUNK:...])
// 2000 blocks x 256 threads, <=64 VGPR -> 32 waves/CU.
// W loads are nontemporal (single-variable change vs R6: restore nt).
__global__ __launch_bounds__(256) void gemv_part_kernel(
    const float* __restrict__ W,
    const float* __restrict__ x,
    float* __restrict__ ws)
{
    const int bid = blockIdx.x;          // 0..1999
    const int row = bid >> 2;
    const int q   = bid & 3;
    const int t   = threadIdx.x;

    const f4* __restrict__ Wq =
        reinterpret_cast<const f4*>(W + (size_t)row * DIM_HID + q * QCHUNK);
    const f4* __restrict__ xq =
        reinterpret_cast<const f4*>(x + q * QCHUNK);

    float s = 0.0f;
#pragma unroll 4
    for (int k = 0; k < 16; ++k) {
        const int idx = t + k * 256;                 // coalesced
        f4 w = __builtin_nontemporal_load(&Wq[idx]); // stream W once
        f4 v = xq[idx];
        s = fmaf(w.x, v.x, s);
        s = fmaf(w.y, v.y, s);
        s = fmaf(w.z, v.z, s);
        s = fmaf(w.w, v.w, s);
    }

#pragma unroll
    for (int off = 32; off > 0; off >>= 1)
        s += __shfl_down(s, off, 64);

    __shared__ float wsum[4];
    const int wave = t >> 6;
    const int lane = t & 63;
    if (lane == 0) wsum[wave] = s;
    __syncthreads();

    if (t == 0)
        ws[bid] = (wsum[0] + wsum[1]) + (wsum[2] + wsum[3]);
}

// Kernel 2: coalesced expand partials. Block ib covers i in [ib*16, ib*16+16);
// thread t owns columns j0=t and j1=t+256. kernels reads coalesced across lanes.
__global__ __launch_bounds__(256) void expand_part_kernel(
    const float* __restrict__ ws,
    const float* __restrict__ bias,
    const float* __restrict__ kernels,
    const int* __restrict__ kw,
    float* __restrict__ partial)
{
    const int ib = blockIdx.x;
    const int t  = threadIdx.x;
    const int j0 = t;
    const int j1 = t + 256;
    const f4* __restrict__ wsv = reinterpret_cast<const f4*>(ws);

    float a0 = 0.0f, a1 = 0.0f;
#pragma unroll
    for (int ii = 0; ii < ITILE; ++ii) {
        const int i = ib * ITILE + ii;
        if (i < NKERS) {
            const f4  p  = wsv[i];                         // 4 gemv partials of row i
            const float yi = ((p.x + p.y) + (p.z + p.w)) + bias[i];
            const int   w  = kw[i];
            const float* krow = kernels + i * NKERS;
            const float k0 = krow[j0];
            const float k1 = (j1 < NKERS) ? krow[j1] : 0.0f;
            if (j0 < w) a0 = fmaf(yi, k0, a0);
            if (j1 < w) a1 = fmaf(yi, k1, a1);
        }
    }
    partial[ib * JPAD + j0] = a0;
    partial[ib * JPAD + j1] = a1;
}

// Kernel 3: z[j] = sum_ib partial[ib*512 + j].
__global__ __launch_bounds__(512) void expand_reduce_kernel(
    const float* __restrict__ partial,
    float* __restrict__ z)
{
    const int j = threadIdx.x;
    if (j >= NKERS) return;
    float s = 0.0f;
#pragma unroll
    for (int ib = 0; ib < NIB; ++ib)
        s += partial[ib * JPAD + j];
    z[j] = s;
}

extern "C" void kernel_launch(void* const* d_in, const int* in_sizes, int n_in,
                              void* d_out, int out_size, void* d_ws, size_t ws_size,
                              hipStream_t stream)
{
    const float* input   = (const float*)d_in[0];  // [65536]
    const float* weight  = (const float*)d_in[1];  // [500, 65536]
    const float* bias    = (const float*)d_in[2];  // [500]
    const float* kernels = (const float*)d_in[3];  // [500, 500]
    const int*   kwidths = (const int*)d_in[4];    // [500]
    float* z  = (float*)d_out;                     // [500]
    float* ws = (float*)d_ws;                      // [0..2000): gemv partials
    float* pz = ws + 4096;                         // [4096..): expand partials

    gemv_part_kernel<<<NKERS * NQ, 256, 0, stream>>>(weight, input, ws);
    expand_part_kernel<<<NIB, 256, 0, stream>>>(ws, bias, kernels, kwidths, pz);
    expand_reduce_kernel<<<1, 512, 0, stream>>>(pz, z);
}

// Round 8
// 27.268 us; speedup vs baseline: 1.2383x; 1.2383x over previous
//
#include <hip/hip_runtime.h>

#define DIM_HID 65536
#define NKERS   500
#define ROWS_PB 4                     // rows per gemv block
#define NCHUNK  16                    // chunks per row
#define CHUNK   (DIM_HID / NCHUNK)    // 4096 floats = 1024 float4 per chunk

typedef float f4 __attribute__((ext_vector_type(4)));

// Kernel 1: partial GEMV, 4 rows x 1/16 row per block.
//   ws[row*16+q] = dot(W[row, q*CHUNK:(q+1)*CHUNK], x[q*CHUNK:...])
// 125*16 = 2000 blocks x 256 threads; launch_bounds(256,8) -> <=64 VGPR,
// 32 waves/CU (the R5-proven occupancy). Each x-load now feeds 4 rows'
// fmas: x-load share of vm instructions drops 50% -> 20%, so more of the
// vmcnt/TA budget streams W. bid&15==q => same-chunk blocks land on the
// same XCD (bid%8 round-robin): x chunk stays in that XCD's L2.
__global__ __launch_bounds__(256, 8) void gemv_part_kernel(
    const float* __restrict__ W,
    const float* __restrict__ x,
    float* __restrict__ ws)
{
    const int bid = blockIdx.x;           // 0..1999
    const int rg  = bid >> 4;             // rowgroup 0..124
    const int q   = bid & 15;             // chunk 0..15
    const int r0  = rg * ROWS_PB;
    const int t   = threadIdx.x;

    const size_t base = (size_t)r0 * DIM_HID + (size_t)q * CHUNK;
    const f4* __restrict__ W0 = reinterpret_cast<const f4*>(W + base);
    const f4* __restrict__ W1 = reinterpret_cast<const f4*>(W + base + DIM_HID);
    const f4* __restrict__ W2 = reinterpret_cast<const f4*>(W + base + 2 * DIM_HID);
    const f4* __restrict__ W3 = reinterpret_cast<const f4*>(W + base + 3 * DIM_HID);
    const f4* __restrict__ xq = reinterpret_cast<const f4*>(x + q * CHUNK);

    float s0 = 0.0f, s1 = 0.0f, s2 = 0.0f, s3 = 0.0f;
#pragma unroll 2
    for (int k = 0; k < 4; ++k) {
        const int idx = t + k * 256;                    // coalesced
        const f4 v  = xq[idx];
        const f4 w0 = __builtin_nontemporal_load(&W0[idx]);
        const f4 w1 = __builtin_nontemporal_load(&W1[idx]);
        const f4 w2 = __builtin_nontemporal_load(&W2[idx]);
        const f4 w3 = __builtin_nontemporal_load(&W3[idx]);
        s0 = fmaf(w0.x, v.x, s0); s0 = fmaf(w0.y, v.y, s0);
        s0 = fmaf(w0.z, v.z, s0); s0 = fmaf(w0.w, v.w, s0);
        s1 = fmaf(w1.x, v.x, s1); s1 = fmaf(w1.y, v.y, s1);
        s1 = fmaf(w1.z, v.z, s1); s1 = fmaf(w1.w, v.w, s1);
        s2 = fmaf(w2.x, v.x, s2); s2 = fmaf(w2.y, v.y, s2);
        s2 = fmaf(w2.z, v.z, s2); s2 = fmaf(w2.w, v.w, s2);
        s3 = fmaf(w3.x, v.x, s3); s3 = fmaf(w3.y, v.y, s3);
        s3 = fmaf(w3.z, v.z, s3); s3 = fmaf(w3.w, v.w, s3);
    }

    // wave reduce all four accumulators
#pragma unroll
    for (int off = 32; off > 0; off >>= 1) {
        s0 += __shfl_down(s0, off, 64);
        s1 += __shfl_down(s1, off, 64);
        s2 += __shfl_down(s2, off, 64);
        s3 += __shfl_down(s3, off, 64);
    }

    __shared__ float wsum[4][4];   // [wave][row]
    const int wave = t >> 6;
    const int lane = t & 63;
    if (lane == 0) {
        wsum[wave][0] = s0; wsum[wave][1] = s1;
        wsum[wave][2] = s2; wsum[wave][3] = s3;
    }
    __syncthreads();

    if (t < 4) {   // thread rr writes row r0+rr
        float a = wsum[0][t] + wsum[1][t] + wsum[2][t] + wsum[3][t];
        ws[(size_t)(r0 + t) * NCHUNK + q] = a;
    }
}

// Kernel 2 (R5 structure): z[j] = sum_i y_i * kernels[i][j] * (j < kw[i]),
// y_i = sum of 16 gemv partials + bias[i]. One block per j, 500x256.
__global__ __launch_bounds__(256) void expand_kernel(
    const float* __restrict__ ws,
    const float* __restrict__ bias,
    const float* __restrict__ kernels,
    const int* __restrict__ kw,
    float* __restrict__ z)
{
    const int j = blockIdx.x;
    const int t = threadIdx.x;
    const f4* __restrict__ wsv = reinterpret_cast<const f4*>(ws);

    float acc = 0.0f;
#pragma unroll
    for (int k = 0; k < 2; ++k) {
        const int i = t + k * 256;
        if (i < NKERS) {
            const f4 p0 = wsv[i * 4 + 0];
            const f4 p1 = wsv[i * 4 + 1];
            const f4 p2 = wsv[i * 4 + 2];
            const f4 p3 = wsv[i * 4 + 3];
            const float yi = (((p0.x + p0.y) + (p0.z + p0.w)) +
                              ((p1.x + p1.y) + (p1.z + p1.w))) +
                             (((p2.x + p2.y) + (p2.z + p2.w)) +
                              ((p3.x + p3.y) + (p3.z + p3.w))) + bias[i];
            const int   w  = kw[i];
            const float kv = kernels[i * NKERS + j];
            if (j < w) acc = fmaf(yi, kv, acc);
        }
    }

#pragma unroll
    for (int off = 32; off > 0; off >>= 1)
        acc += __shfl_down(acc, off, 64);

    __shared__ float wsum[4];
    const int wave = t >> 6;
    const int lane = t & 63;
    if (lane == 0) wsum[wave] = acc;
    __syncthreads();

    if (t == 0)
        z[j] = (wsum[0] + wsum[1]) + (wsum[2] + wsum[3]);
}

extern "C" void kernel_launch(void* const* d_in, const int* in_sizes, int n_in,
                              void* d_out, int out_size, void* d_ws, size_t ws_size,
                              hipStream_t stream)
{
    const float* input   = (const float*)d_in[0];  // [65536]
    const float* weight  = (const float*)d_in[1];  // [500, 65536]
    const float* bias    = (const float*)d_in[2];  // [500]
    const float* kernels = (const float*)d_in[3];  // [500, 500]
    const int*   kwidths = (const int*)d_in[4];    // [500]
    float* z  = (float*)d_out;                     // [500]
    float* ws = (float*)d_ws;                      // [500*16] gemv partials

    gemv_part_kernel<<<(NKERS / ROWS_PB) * NCHUNK, 256, 0, stream>>>(weight, input, ws);
    expand_kernel<<<NKERS, 256, 0, stream>>>(ws, bias, kernels, kwidths, z);
}